// Round 3
// baseline (3778.281 us; speedup 1.0000x reference)
//
#include <hip/hip_runtime.h>
#include <hip/hip_bf16.h>
#include <cmath>

#define DEVI static __device__ __forceinline__

constexpr int Dn = 32, HIDn = 128, OUTn = 64;
constexpr int NCn = 50000, NDn = 50000, En = 400000;

// monotonic float->uint mapping for atomicMax on floats (handles signs)
DEVI unsigned fmap(float f) {
  int i = __float_as_int(f);
  return (i < 0) ? ~((unsigned)i) : (((unsigned)i) | 0x80000000u);
}
DEVI float fdecode(unsigned u) {
  int i = (u & 0x80000000u) ? (int)(u & 0x7fffffffu) : (int)(~u);
  return __int_as_float(i);
}

// ---------------- GEMM: C[N,KO] = A[N,KI] @ W[KI,KO] + b (fp32 accum) ----
template<int KI>
__global__ __launch_bounds__(256)
void gemm_bias(const float* __restrict__ A, const float* __restrict__ W,
               const float* __restrict__ b, float* __restrict__ C,
               int N, int KO)
{
  __shared__ float At[32][68];   // A^T chunk: [k][row]
  __shared__ float Ws[32][68];   // W chunk:   [k][col]
  const int row0 = blockIdx.x * 64;
  const int col0 = blockIdx.y * 64;
  const int tid  = threadIdx.x;
  const int r0 = (tid >> 4) << 2;
  const int c0 = (tid & 15) << 2;
  float acc[4][4] = {{0.f, 0.f, 0.f, 0.f}};

  for (int k0 = 0; k0 < KI; k0 += 32) {
    {
      const int r  = tid >> 2;
      const int kq = (tid & 3) << 3;
      const int row = row0 + r;
      float tmp[8];
      if (row < N) {
        const float* ap = A + (size_t)row * KI + k0 + kq;
        #pragma unroll
        for (int i = 0; i < 8; ++i) tmp[i] = ap[i];
      } else {
        #pragma unroll
        for (int i = 0; i < 8; ++i) tmp[i] = 0.f;
      }
      #pragma unroll
      for (int i = 0; i < 8; ++i) At[kq + i][r] = tmp[i];
    }
    {
      const int k  = tid >> 3;
      const int cq = (tid & 7) << 3;
      const float* wp = W + (size_t)(k0 + k) * KO + col0 + cq;
      #pragma unroll
      for (int i = 0; i < 8; ++i) Ws[k][cq + i] = wp[i];
    }
    __syncthreads();
    #pragma unroll
    for (int k = 0; k < 32; ++k) {
      float av[4], wv[4];
      #pragma unroll
      for (int i = 0; i < 4; ++i) av[i] = At[k][r0 + i];
      #pragma unroll
      for (int j = 0; j < 4; ++j) wv[j] = Ws[k][c0 + j];
      #pragma unroll
      for (int i = 0; i < 4; ++i) {
        #pragma unroll
        for (int j = 0; j < 4; ++j) acc[i][j] += av[i] * wv[j];
      }
    }
    __syncthreads();
  }

  #pragma unroll
  for (int i = 0; i < 4; ++i) {
    const int row = row0 + r0 + i;
    if (row >= N) continue;
    #pragma unroll
    for (int j = 0; j < 4; ++j) {
      const int col = col0 + c0 + j;
      C[(size_t)row * KO + col] = acc[i][j] + b[col];
    }
  }
}

// ---- per-(node,head) dot: out[n,h] = sum_d h[n, h*32+d] * a[h*32+d] ----
__global__ void dot_ah(const float* __restrict__ h, const float* __restrict__ a,
                       float* __restrict__ out, int NH)
{
  int idx = blockIdx.x * blockDim.x + threadIdx.x;
  if (idx >= NH) return;
  int n = idx >> 2, hh = idx & 3;
  const float* hp = h + (size_t)n * HIDn + hh * Dn;
  float s = 0.f;
  #pragma unroll
  for (int i = 0; i < Dn; ++i) s += hp[i] * a[hh * Dn + i];
  out[idx] = s;
}

// ---- edge pass 1: logits + segment max over dst (uint-mapped atomicMax) --
__global__ void edge_logit_max(const int* __restrict__ ei,
                               const float* __restrict__ sdot,
                               const float* __restrict__ ddot,
                               unsigned* __restrict__ m)
{
  int e = blockIdx.x * blockDim.x + threadIdx.x;
  if (e >= En) return;
  int s = ei[e], d = ei[En + e];
  #pragma unroll
  for (int hh = 0; hh < 4; ++hh) {
    float l = sdot[s * 4 + hh] + ddot[d * 4 + hh];
    l = (l > 0.f) ? l : 0.2f * l;                      // leaky_relu(0.2)
    atomicMax(&m[d * 4 + hh], fmap(l));
  }
}

// ---- edge pass 2: e = exp(l - max), segment-sum over dst ----------------
__global__ void edge_exp_sum(const int* __restrict__ ei,
                             const float* __restrict__ sdot,
                             const float* __restrict__ ddot,
                             const unsigned* __restrict__ m,
                             float* __restrict__ sden,
                             float* __restrict__ ebuf)
{
  int e = blockIdx.x * blockDim.x + threadIdx.x;
  if (e >= En) return;
  int s = ei[e], d = ei[En + e];
  #pragma unroll
  for (int hh = 0; hh < 4; ++hh) {
    float l = sdot[s * 4 + hh] + ddot[d * 4 + hh];
    l = (l > 0.f) ? l : 0.2f * l;
    float ex = expf(fminf(l - fdecode(m[d * 4 + hh]), 0.f));
    ebuf[e * 4 + hh] = ex;
    atomicAdd(&sden[d * 4 + hh], ex);
  }
}

// ---- edge pass 3: out[dst] += h_src[src] * alpha (one wave per edge) ----
__global__ __launch_bounds__(256)
void edge_scatter(const int* __restrict__ ei, const float* __restrict__ hsrc,
                  const float* __restrict__ ebuf, const float* __restrict__ sden,
                  float* __restrict__ out)
{
  int gid  = blockIdx.x * 256 + threadIdx.x;
  int e    = gid >> 6;
  if (e >= En) return;
  int lane = gid & 63;
  int s = ei[e], d = ei[En + e];
  #pragma unroll
  for (int half = 0; half < 2; ++half) {
    int c  = lane + half * 64;
    int hh = c >> 5;
    float alpha = ebuf[e * 4 + hh] / (sden[d * 4 + hh] + 1e-16f);
    atomicAdd(&out[(size_t)d * HIDn + c], hsrc[(size_t)s * HIDn + c] * alpha);
  }
}

__global__ void relu_k(float* __restrict__ x, int n)
{
  int i = blockIdx.x * blockDim.x + threadIdx.x;
  if (i < n) x[i] = fmaxf(x[i], 0.f);
}

// ---- semantic-attention score: slot += mean_n( q . tanh(o[n]@kW + kb) ) --
__global__ __launch_bounds__(256)
void score_kernel(const float* __restrict__ o, const float* __restrict__ kW,
                  const float* __restrict__ kb, const float* __restrict__ q,
                  int N, float* __restrict__ slot)
{
  __shared__ float so[2][128];
  __shared__ float part[4];
  int tid = threadIdx.x;
  int nl = tid >> 7, c = tid & 127;
  int node = blockIdx.x * 2 + nl;
  so[nl][c] = (node < N) ? o[(size_t)node * HIDn + c] : 0.f;
  __syncthreads();
  float acc = kb[c];
  for (int k = 0; k < 128; ++k)
    acc += so[nl][k] * kW[k * 128 + c];
  float v = (node < N) ? q[c] * tanhf(acc) : 0.f;
  for (int off = 32; off > 0; off >>= 1) v += __shfl_down(v, off);
  int wid = tid >> 6, lane = tid & 63;
  if (lane == 0) part[wid] = v;
  __syncthreads();
  if (tid == 0)
    atomicAdd(slot, (part[0] + part[1] + part[2] + part[3]) * (1.0f / (float)N));
}

__global__ void softmax2_kernel(float* sb)   // sb[0],sb[1] -> weights sb[2],sb[3]
{
  float s0 = sb[0], s1 = sb[1];
  float mx = fmaxf(s0, s1);
  float e0 = expf(s0 - mx), e1 = expf(s1 - mx);
  float inv = 1.f / (e0 + e1);
  sb[2] = e0 * inv;
  sb[3] = e1 * inv;
}

__global__ void combine2_elu(const float* __restrict__ a, const float* __restrict__ b,
                             const float* __restrict__ w, float* __restrict__ out, int n)
{
  int i = blockIdx.x * blockDim.x + threadIdx.x;
  if (i >= n) return;
  float x = w[2] * a[i] + w[3] * b[i];
  out[i] = (x > 0.f) ? x : expm1f(x);
}

__global__ void elu_copy(const float* __restrict__ a, float* __restrict__ out, int n)
{
  int i = blockIdx.x * blockDim.x + threadIdx.x;
  if (i >= n) return;
  float x = a[i];
  out[i] = (x > 0.f) ? x : expm1f(x);
}

// ---- final projection (+ optional L2 normalize), fp32 store -------------
template<bool NORM>
__global__ __launch_bounds__(256)
void proj_kernel(const float* __restrict__ feat, const float* __restrict__ pW,
                 const float* __restrict__ pb, float* __restrict__ out, int N)
{
  __shared__ float row[4][128];
  int tid = threadIdx.x;
  int wid = tid >> 6, lane = tid & 63;
  int node = blockIdx.x * 4 + wid;
  if (node < N) {
    row[wid][lane]      = feat[(size_t)node * HIDn + lane];
    row[wid][lane + 64] = feat[(size_t)node * HIDn + lane + 64];
  }
  __syncthreads();
  if (node >= N) return;
  float acc = pb[lane];
  #pragma unroll
  for (int k = 0; k < 128; ++k)
    acc += row[wid][k] * pW[k * OUTn + lane];
  if (NORM) {
    float ss = acc * acc;
    #pragma unroll
    for (int off = 1; off < 64; off <<= 1) ss += __shfl_xor(ss, off);
    acc *= 1.f / fmaxf(sqrtf(ss), 1e-12f);
  }
  out[(size_t)node * OUTn + lane] = acc;
}

// ---- one full GAT edge-attention op -------------------------------------
static void run_edge_att(hipStream_t stream,
                         const float* hsrc, const float* hdst,
                         const float* a_s, const float* a_d, const int* ei,
                         int Nsrc, int Ndst, float* outb,
                         float* sdot, float* ddot, unsigned* mbuf,
                         float* sden, float* ebuf)
{
  dot_ah<<<(Nsrc * 4 + 255) / 256, 256, 0, stream>>>(hsrc, a_s, sdot, Nsrc * 4);
  dot_ah<<<(Ndst * 4 + 255) / 256, 256, 0, stream>>>(hdst, a_d, ddot, Ndst * 4);
  hipMemsetAsync(mbuf, 0, (size_t)Ndst * 4 * sizeof(unsigned), stream);
  edge_logit_max<<<(En + 255) / 256, 256, 0, stream>>>(ei, sdot, ddot, mbuf);
  hipMemsetAsync(sden, 0, (size_t)Ndst * 4 * sizeof(float), stream);
  edge_exp_sum<<<(En + 255) / 256, 256, 0, stream>>>(ei, sdot, ddot, mbuf, sden, ebuf);
  hipMemsetAsync(outb, 0, (size_t)Ndst * HIDn * sizeof(float), stream);
  edge_scatter<<<((size_t)En * 64 + 255) / 256, 256, 0, stream>>>(ei, hsrc, ebuf, sden, outb);
  relu_k<<<((size_t)Ndst * HIDn + 255) / 256, 256, 0, stream>>>(outb, Ndst * HIDn);
}

extern "C" void kernel_launch(void* const* d_in, const int* in_sizes, int n_in,
                              void* d_out, int out_size, void* d_ws, size_t ws_size,
                              hipStream_t stream)
{
  const float* xc    = (const float*)d_in[0];
  const float* xd    = (const float*)d_in[1];
  const int*   ei_cc = (const int*)d_in[2];
  const int*   ei_dc = (const int*)d_in[3];
  const int*   ei_cd = (const int*)d_in[4];
  const float* W1c = (const float*)d_in[5];  const float* b1c = (const float*)d_in[6];
  const float* W1d = (const float*)d_in[7];  const float* b1d = (const float*)d_in[8];
  const float* a1s_cc = (const float*)d_in[9];  const float* a1d_cc = (const float*)d_in[10];
  const float* a1s_dc = (const float*)d_in[11]; const float* a1d_dc = (const float*)d_in[12];
  const float* a1s_cd = (const float*)d_in[13]; const float* a1d_cd = (const float*)d_in[14];
  const float* k1W = (const float*)d_in[15]; const float* k1b = (const float*)d_in[16];
  const float* q1  = (const float*)d_in[17];
  const float* W2c = (const float*)d_in[18]; const float* b2c = (const float*)d_in[19];
  const float* W2d = (const float*)d_in[20]; const float* b2d = (const float*)d_in[21];
  const float* a2s_cc = (const float*)d_in[22]; const float* a2d_cc = (const float*)d_in[23];
  const float* a2s_dc = (const float*)d_in[24]; const float* a2d_dc = (const float*)d_in[25];
  const float* a2s_cd = (const float*)d_in[26]; const float* a2d_cd = (const float*)d_in[27];
  const float* k2W = (const float*)d_in[28]; const float* k2b = (const float*)d_in[29];
  const float* q2  = (const float*)d_in[30];
  const float* pW  = (const float*)d_in[31]; const float* pb  = (const float*)d_in[32];

  // workspace layout (fp32), ~138 MiB total
  float* ws = (float*)d_ws;
  const size_t NB = (size_t)NCn * HIDn;           // 6,400,000 floats per node buffer
  float* B0 = ws;
  float* B1 = ws + NB;
  float* B2 = ws + 2 * NB;
  float* B3 = ws + 3 * NB;
  float* B4 = ws + 4 * NB;
  float* sml = ws + 5 * NB;
  float*    sdot  = sml;                       // N*4
  float*    ddot  = sml + 200000;              // N*4
  unsigned* mbuf  = (unsigned*)(sml + 400000); // N*4
  float*    sden  = sml + 600000;              // N*4
  float*    ebuf  = sml + 800000;              // E*4
  float*    scoreB = sml + 2400000;            // [s0,s1,w0,w1]

  const dim3 gemmGrid((NCn + 63) / 64, HIDn / 64);

  // ---------------- layer 1 ----------------
  gemm_bias<256><<<gemmGrid, 256, 0, stream>>>(xc, W1c, b1c, B0, NCn, HIDn);
  gemm_bias<256><<<gemmGrid, 256, 0, stream>>>(xd, W1d, b1d, B1, NDn, HIDn);

  run_edge_att(stream, B0, B0, a1s_cc, a1d_cc, ei_cc, NCn, NCn, B2, sdot, ddot, mbuf, sden, ebuf);
  run_edge_att(stream, B1, B0, a1s_dc, a1d_dc, ei_dc, NDn, NCn, B3, sdot, ddot, mbuf, sden, ebuf);
  run_edge_att(stream, B0, B1, a1s_cd, a1d_cd, ei_cd, NCn, NDn, B4, sdot, ddot, mbuf, sden, ebuf);

  hipMemsetAsync(scoreB, 0, 2 * sizeof(float), stream);
  score_kernel<<<(NCn + 1) / 2, 256, 0, stream>>>(B2, k1W, k1b, q1, NCn, scoreB + 0);
  score_kernel<<<(NCn + 1) / 2, 256, 0, stream>>>(B3, k1W, k1b, q1, NCn, scoreB + 1);
  softmax2_kernel<<<1, 1, 0, stream>>>(scoreB);
  combine2_elu<<<((int)NB + 255) / 256, 256, 0, stream>>>(B2, B3, scoreB, B0, (int)NB);
  elu_copy<<<((int)NB + 255) / 256, 256, 0, stream>>>(B4, B1, (int)NB);

  // ---------------- layer 2 ----------------
  gemm_bias<128><<<gemmGrid, 256, 0, stream>>>(B0, W2c, b2c, B2, NCn, HIDn);
  gemm_bias<128><<<gemmGrid, 256, 0, stream>>>(B1, W2d, b2d, B3, NDn, HIDn);

  run_edge_att(stream, B2, B2, a2s_cc, a2d_cc, ei_cc, NCn, NCn, B4, sdot, ddot, mbuf, sden, ebuf);
  run_edge_att(stream, B3, B2, a2s_dc, a2d_dc, ei_dc, NDn, NCn, B0, sdot, ddot, mbuf, sden, ebuf);
  run_edge_att(stream, B2, B3, a2s_cd, a2d_cd, ei_cd, NCn, NDn, B1, sdot, ddot, mbuf, sden, ebuf);

  hipMemsetAsync(scoreB, 0, 2 * sizeof(float), stream);
  score_kernel<<<(NCn + 1) / 2, 256, 0, stream>>>(B4, k2W, k2b, q2, NCn, scoreB + 0);
  score_kernel<<<(NCn + 1) / 2, 256, 0, stream>>>(B0, k2W, k2b, q2, NCn, scoreB + 1);
  softmax2_kernel<<<1, 1, 0, stream>>>(scoreB);
  combine2_elu<<<((int)NB + 255) / 256, 256, 0, stream>>>(B4, B0, scoreB, B2, (int)NB);
  elu_copy<<<((int)NB + 255) / 256, 256, 0, stream>>>(B1, B3, (int)NB);

  // ---------------- projection + normalize ----------------
  proj_kernel<true><<<(NCn + 3) / 4, 256, 0, stream>>>(B2, pW, pb, (float*)d_out, NCn);
  proj_kernel<false><<<(NDn + 3) / 4, 256, 0, stream>>>(B3, pW, pb,
                                                        (float*)d_out + (size_t)NCn * OUTn, NDn);
}

// Round 4
// 2427.133 us; speedup vs baseline: 1.5567x; 1.5567x over previous
//
#include <hip/hip_runtime.h>
#include <cmath>

#define DEVI static __device__ __forceinline__

constexpr int Dn = 32, HIDn = 128, OUTn = 64;
constexpr int NCn = 50000, NDn = 50000, En = 400000;

// monotonic float->uint mapping for atomicMax on floats (handles signs)
DEVI unsigned fmap(float f) {
  int i = __float_as_int(f);
  return (i < 0) ? ~((unsigned)i) : (((unsigned)i) | 0x80000000u);
}
DEVI float fdecode(unsigned u) {
  int i = (u & 0x80000000u) ? (int)(u & 0x7fffffffu) : (int)(~u);
  return __int_as_float(i);
}

// ---------------- GEMM: C[N,KO] = A[N,KI] @ W[KI,KO] + b (fp32 accum) ----
template<int KI>
__global__ __launch_bounds__(256)
void gemm_bias(const float* __restrict__ A, const float* __restrict__ W,
               const float* __restrict__ b, float* __restrict__ C,
               int N, int KO)
{
  __shared__ float At[32][68];   // A^T chunk: [k][row]
  __shared__ float Ws[32][68];   // W chunk:   [k][col]
  const int row0 = blockIdx.x * 64;
  const int col0 = blockIdx.y * 64;
  const int tid  = threadIdx.x;
  const int r0 = (tid >> 4) << 2;
  const int c0 = (tid & 15) << 2;
  float acc[4][4] = {{0.f, 0.f, 0.f, 0.f}};

  for (int k0 = 0; k0 < KI; k0 += 32) {
    {
      const int r  = tid >> 2;
      const int kq = (tid & 3) << 3;
      const int row = row0 + r;
      float tmp[8];
      if (row < N) {
        const float* ap = A + (size_t)row * KI + k0 + kq;
        #pragma unroll
        for (int i = 0; i < 8; ++i) tmp[i] = ap[i];
      } else {
        #pragma unroll
        for (int i = 0; i < 8; ++i) tmp[i] = 0.f;
      }
      #pragma unroll
      for (int i = 0; i < 8; ++i) At[kq + i][r] = tmp[i];
    }
    {
      const int k  = tid >> 3;
      const int cq = (tid & 7) << 3;
      const float* wp = W + (size_t)(k0 + k) * KO + col0 + cq;
      #pragma unroll
      for (int i = 0; i < 8; ++i) Ws[k][cq + i] = wp[i];
    }
    __syncthreads();
    #pragma unroll
    for (int k = 0; k < 32; ++k) {
      float av[4], wv[4];
      #pragma unroll
      for (int i = 0; i < 4; ++i) av[i] = At[k][r0 + i];
      #pragma unroll
      for (int j = 0; j < 4; ++j) wv[j] = Ws[k][c0 + j];
      #pragma unroll
      for (int i = 0; i < 4; ++i) {
        #pragma unroll
        for (int j = 0; j < 4; ++j) acc[i][j] += av[i] * wv[j];
      }
    }
    __syncthreads();
  }

  #pragma unroll
  for (int i = 0; i < 4; ++i) {
    const int row = row0 + r0 + i;
    if (row >= N) continue;
    #pragma unroll
    for (int j = 0; j < 4; ++j) {
      const int col = col0 + c0 + j;
      C[(size_t)row * KO + col] = acc[i][j] + b[col];
    }
  }
}

// ---- per-(node,head) dot: out[n,h] = sum_d h[n, h*32+d] * a[h*32+d] ----
__global__ void dot_ah(const float* __restrict__ h, const float* __restrict__ a,
                       float* __restrict__ out, int NH)
{
  int idx = blockIdx.x * blockDim.x + threadIdx.x;
  if (idx >= NH) return;
  int n = idx >> 2, hh = idx & 3;
  const float* hp = h + (size_t)n * HIDn + hh * Dn;
  float s = 0.f;
  #pragma unroll
  for (int i = 0; i < Dn; ++i) s += hp[i] * a[hh * Dn + i];
  out[idx] = s;
}

// ---- edge pass 1: logits + segment max over dst (uint-mapped atomicMax) --
__global__ void edge_logit_max(const int* __restrict__ ei,
                               const float* __restrict__ sdot,
                               const float* __restrict__ ddot,
                               unsigned* __restrict__ m)
{
  int e = blockIdx.x * blockDim.x + threadIdx.x;
  if (e >= En) return;
  int s = ei[e], d = ei[En + e];
  #pragma unroll
  for (int hh = 0; hh < 4; ++hh) {
    float l = sdot[s * 4 + hh] + ddot[d * 4 + hh];
    l = (l > 0.f) ? l : 0.2f * l;                      // leaky_relu(0.2)
    atomicMax(&m[d * 4 + hh], fmap(l));
  }
}

// ---- edge pass 2: e = exp(l - max), segment-sum over dst ----------------
__global__ void edge_exp_sum(const int* __restrict__ ei,
                             const float* __restrict__ sdot,
                             const float* __restrict__ ddot,
                             const unsigned* __restrict__ m,
                             float* __restrict__ sden,
                             float* __restrict__ ebuf)
{
  int e = blockIdx.x * blockDim.x + threadIdx.x;
  if (e >= En) return;
  int s = ei[e], d = ei[En + e];
  #pragma unroll
  for (int hh = 0; hh < 4; ++hh) {
    float l = sdot[s * 4 + hh] + ddot[d * 4 + hh];
    l = (l > 0.f) ? l : 0.2f * l;
    float ex = expf(fminf(l - fdecode(m[d * 4 + hh]), 0.f));
    ebuf[e * 4 + hh] = ex;
    atomicAdd(&sden[d * 4 + hh], ex);
  }
}

// ================= CSR build (dst-bucketed edge lists) ===================
__global__ void hist_deg(const int* __restrict__ ei, int* __restrict__ deg)
{
  int e = blockIdx.x * blockDim.x + threadIdx.x;
  if (e < En) atomicAdd(&deg[ei[En + e]], 1);
}

// single-block exclusive scan: offs[0]=0, offs[i+1]=sum(deg[0..i])
__global__ void scan_offsets(const int* __restrict__ deg, int* __restrict__ offs, int n)
{
  __shared__ int wsum[16];
  __shared__ int carry_sh;
  int tid = threadIdx.x;
  if (tid == 0) { carry_sh = 0; offs[0] = 0; }
  __syncthreads();
  const int nw = blockDim.x >> 6;
  int lane = tid & 63, w = tid >> 6;
  for (int base = 0; base < n; base += blockDim.x) {
    int i = base + tid;
    int v = (i < n) ? deg[i] : 0;
    int x = v;
    #pragma unroll
    for (int off = 1; off < 64; off <<= 1) {
      int y = __shfl_up(x, off);
      if (lane >= off) x += y;
    }
    if (lane == 63) wsum[w] = x;
    __syncthreads();
    if (tid == 0) {
      int s = carry_sh;
      for (int ww = 0; ww < nw; ++ww) { int t = wsum[ww]; wsum[ww] = s; s += t; }
      carry_sh = s;
    }
    __syncthreads();
    if (i < n) offs[i + 1] = wsum[w] + x;
    __syncthreads();
  }
}

__global__ void fill_elist(const int* __restrict__ ei, const int* __restrict__ offs,
                           int* __restrict__ cursor, int2* __restrict__ elist)
{
  int e = blockIdx.x * blockDim.x + threadIdx.x;
  if (e >= En) return;
  int s = ei[e], d = ei[En + e];
  int p = atomicAdd(&cursor[d], 1);
  elist[offs[d] + p] = make_int2(s, e);
}

// ---- edge pass 3 (CSR): per-dst wave gathers alpha*h_src, fused relu ----
__global__ __launch_bounds__(256)
void csr_gather(const int* __restrict__ offs, const int2* __restrict__ elist,
                const float* __restrict__ hsrc, const float* __restrict__ ebuf,
                const float* __restrict__ sden, float* __restrict__ out, int Ndst)
{
  int wave = (blockIdx.x * 256 + threadIdx.x) >> 6;
  if (wave >= Ndst) return;
  int lane = threadIdx.x & 63;
  int dst = wave;
  int h = lane >> 4;                       // channels 2*lane, 2*lane+1 -> head (2*lane)>>5
  float dinv = 1.f / (sden[dst * 4 + h] + 1e-16f);
  int i0 = offs[dst], i1 = offs[dst + 1];
  float a0 = 0.f, a1 = 0.f;
  for (int i = i0; i < i1; ++i) {
    int2 se = elist[i];
    float alpha = ebuf[(size_t)se.y * 4 + h] * dinv;
    float2 hv = *(const float2*)(hsrc + (size_t)se.x * HIDn + lane * 2);
    a0 += hv.x * alpha;
    a1 += hv.y * alpha;
  }
  float2 o;
  o.x = fmaxf(a0, 0.f);
  o.y = fmaxf(a1, 0.f);
  *(float2*)(out + (size_t)dst * HIDn + lane * 2) = o;
}

// ---- fallback edge pass 3 (atomic scatter) + relu ----------------------
__global__ __launch_bounds__(256)
void edge_scatter(const int* __restrict__ ei, const float* __restrict__ hsrc,
                  const float* __restrict__ ebuf, const float* __restrict__ sden,
                  float* __restrict__ out)
{
  int gid  = blockIdx.x * 256 + threadIdx.x;
  int e    = gid >> 6;
  if (e >= En) return;
  int lane = gid & 63;
  int s = ei[e], d = ei[En + e];
  #pragma unroll
  for (int half = 0; half < 2; ++half) {
    int c  = lane + half * 64;
    int hh = c >> 5;
    float alpha = ebuf[e * 4 + hh] / (sden[d * 4 + hh] + 1e-16f);
    atomicAdd(&out[(size_t)d * HIDn + c], hsrc[(size_t)s * HIDn + c] * alpha);
  }
}

__global__ void relu_k(float* __restrict__ x, int n)
{
  int i = blockIdx.x * blockDim.x + threadIdx.x;
  if (i < n) x[i] = fmaxf(x[i], 0.f);
}

// ---- semantic-attention score, kW staged in LDS (column-half per block) --
// score = (1/N) * sum_n sum_c q[c]*tanh((o@kW+kb)[n,c])  -- separable in c.
// Even blocks handle c in [0,64), odd blocks [64,128).
__global__ __launch_bounds__(256)
void score_lds(const float* __restrict__ o, const float* __restrict__ kW,
               const float* __restrict__ kb, const float* __restrict__ q,
               int N, float* __restrict__ slot)
{
  __shared__ float kWs[128 * 64];
  __shared__ float rows[4][128];
  __shared__ float kbs[64], qs[64];
  __shared__ float partw[4];
  const int tid = threadIdx.x;
  const int ch  = blockIdx.x & 1;
  for (int i = tid * 4; i < 8192; i += 1024) {
    int k = i >> 6, cl = i & 63;
    *(float4*)&kWs[i] = *(const float4*)&kW[k * 128 + ch * 64 + cl];
  }
  if (tid < 64) { kbs[tid] = kb[ch * 64 + tid]; qs[tid] = q[ch * 64 + tid]; }
  __syncthreads();
  const int nl = tid >> 6, cl = tid & 63;
  const int nb = blockIdx.x >> 1, NBLK = gridDim.x >> 1;
  float part = 0.f;
  for (int n0 = nb * 4; n0 < N; n0 += NBLK * 4) {
    int node = n0 + nl;
    rows[nl][cl]      = (node < N) ? o[(size_t)node * HIDn + cl]      : 0.f;
    rows[nl][cl + 64] = (node < N) ? o[(size_t)node * HIDn + cl + 64] : 0.f;
    __syncthreads();
    float acc = kbs[cl];
    #pragma unroll 4
    for (int k = 0; k < 128; ++k)
      acc += rows[nl][k] * kWs[k * 64 + cl];
    if (node < N) part += qs[cl] * tanhf(acc);
    __syncthreads();
  }
  #pragma unroll
  for (int off = 32; off > 0; off >>= 1) part += __shfl_down(part, off);
  if (cl == 0) partw[nl] = part;
  __syncthreads();
  if (tid == 0)
    atomicAdd(slot, (partw[0] + partw[1] + partw[2] + partw[3]) * (1.f / (float)N));
}

__global__ void softmax2_kernel(float* sb)   // sb[0],sb[1] -> weights sb[2],sb[3]
{
  float s0 = sb[0], s1 = sb[1];
  float mx = fmaxf(s0, s1);
  float e0 = expf(s0 - mx), e1 = expf(s1 - mx);
  float inv = 1.f / (e0 + e1);
  sb[2] = e0 * inv;
  sb[3] = e1 * inv;
}

__global__ void combine2_elu(const float* __restrict__ a, const float* __restrict__ b,
                             const float* __restrict__ w, float* __restrict__ out, int n)
{
  int i = blockIdx.x * blockDim.x + threadIdx.x;
  if (i >= n) return;
  float x = w[2] * a[i] + w[3] * b[i];
  out[i] = (x > 0.f) ? x : expm1f(x);
}

__global__ void elu_copy(const float* __restrict__ a, float* __restrict__ out, int n)
{
  int i = blockIdx.x * blockDim.x + threadIdx.x;
  if (i >= n) return;
  float x = a[i];
  out[i] = (x > 0.f) ? x : expm1f(x);
}

// ---- final projection (+ optional L2 normalize), pW staged in LDS -------
template<bool NORM>
__global__ __launch_bounds__(256)
void proj_lds(const float* __restrict__ feat, const float* __restrict__ pW,
              const float* __restrict__ pb, float* __restrict__ out, int N)
{
  __shared__ float pWs[128 * 64];
  __shared__ float rows[4][128];
  __shared__ float pbs[64];
  const int tid = threadIdx.x;
  for (int i = tid * 4; i < 8192; i += 1024)
    *(float4*)&pWs[i] = *(const float4*)&pW[i];
  if (tid < 64) pbs[tid] = pb[tid];
  __syncthreads();
  const int wid = tid >> 6, lane = tid & 63;
  for (int n0 = blockIdx.x * 4; n0 < N; n0 += gridDim.x * 4) {
    int node = n0 + wid;
    if (node < N) {
      rows[wid][lane]      = feat[(size_t)node * HIDn + lane];
      rows[wid][lane + 64] = feat[(size_t)node * HIDn + lane + 64];
    }
    __syncthreads();
    if (node < N) {
      float acc = pbs[lane];
      #pragma unroll 4
      for (int k = 0; k < 128; ++k)
        acc += rows[wid][k] * pWs[k * 64 + lane];
      if (NORM) {
        float ss = acc * acc;
        #pragma unroll
        for (int off = 1; off < 64; off <<= 1) ss += __shfl_xor(ss, off);
        acc *= 1.f / fmaxf(sqrtf(ss), 1e-12f);
      }
      out[(size_t)node * OUTn + lane] = acc;
    }
    __syncthreads();
  }
}

// ---- one full GAT edge-attention op -------------------------------------
static void run_edge_att(hipStream_t stream,
                         const float* hsrc, const float* hdst,
                         const float* a_s, const float* a_d, const int* ei,
                         const int* offs, const int2* elist,   // null -> fallback
                         int Nsrc, int Ndst, float* outb,
                         float* sdot, float* ddot, unsigned* mbuf,
                         float* sden, float* ebuf)
{
  dot_ah<<<(Nsrc * 4 + 255) / 256, 256, 0, stream>>>(hsrc, a_s, sdot, Nsrc * 4);
  dot_ah<<<(Ndst * 4 + 255) / 256, 256, 0, stream>>>(hdst, a_d, ddot, Ndst * 4);
  hipMemsetAsync(mbuf, 0, (size_t)Ndst * 4 * sizeof(unsigned), stream);
  edge_logit_max<<<(En + 255) / 256, 256, 0, stream>>>(ei, sdot, ddot, mbuf);
  hipMemsetAsync(sden, 0, (size_t)Ndst * 4 * sizeof(float), stream);
  edge_exp_sum<<<(En + 255) / 256, 256, 0, stream>>>(ei, sdot, ddot, mbuf, sden, ebuf);
  if (elist) {
    csr_gather<<<(Ndst + 3) / 4, 256, 0, stream>>>(offs, elist, hsrc, ebuf, sden, outb, Ndst);
  } else {
    hipMemsetAsync(outb, 0, (size_t)Ndst * HIDn * sizeof(float), stream);
    edge_scatter<<<((size_t)En * 64 + 255) / 256, 256, 0, stream>>>(ei, hsrc, ebuf, sden, outb);
    relu_k<<<((size_t)Ndst * HIDn + 255) / 256, 256, 0, stream>>>(outb, Ndst * HIDn);
  }
}

static void build_csr(hipStream_t stream, const int* ei, int* offs, int2* elist, int* tmp)
{
  hipMemsetAsync(tmp, 0, 50000 * sizeof(int), stream);
  hist_deg<<<(En + 255) / 256, 256, 0, stream>>>(ei, tmp);
  scan_offsets<<<1, 1024, 0, stream>>>(tmp, offs, 50000);
  hipMemsetAsync(tmp, 0, 50000 * sizeof(int), stream);
  fill_elist<<<(En + 255) / 256, 256, 0, stream>>>(ei, offs, tmp, elist);
}

extern "C" void kernel_launch(void* const* d_in, const int* in_sizes, int n_in,
                              void* d_out, int out_size, void* d_ws, size_t ws_size,
                              hipStream_t stream)
{
  const float* xc    = (const float*)d_in[0];
  const float* xd    = (const float*)d_in[1];
  const int*   ei_cc = (const int*)d_in[2];
  const int*   ei_dc = (const int*)d_in[3];
  const int*   ei_cd = (const int*)d_in[4];
  const float* W1c = (const float*)d_in[5];  const float* b1c = (const float*)d_in[6];
  const float* W1d = (const float*)d_in[7];  const float* b1d = (const float*)d_in[8];
  const float* a1s_cc = (const float*)d_in[9];  const float* a1d_cc = (const float*)d_in[10];
  const float* a1s_dc = (const float*)d_in[11]; const float* a1d_dc = (const float*)d_in[12];
  const float* a1s_cd = (const float*)d_in[13]; const float* a1d_cd = (const float*)d_in[14];
  const float* k1W = (const float*)d_in[15]; const float* k1b = (const float*)d_in[16];
  const float* q1  = (const float*)d_in[17];
  const float* W2c = (const float*)d_in[18]; const float* b2c = (const float*)d_in[19];
  const float* W2d = (const float*)d_in[20]; const float* b2d = (const float*)d_in[21];
  const float* a2s_cc = (const float*)d_in[22]; const float* a2d_cc = (const float*)d_in[23];
  const float* a2s_dc = (const float*)d_in[24]; const float* a2d_dc = (const float*)d_in[25];
  const float* a2s_cd = (const float*)d_in[26]; const float* a2d_cd = (const float*)d_in[27];
  const float* k2W = (const float*)d_in[28]; const float* k2b = (const float*)d_in[29];
  const float* q2  = (const float*)d_in[30];
  const float* pW  = (const float*)d_in[31]; const float* pb  = (const float*)d_in[32];

  // workspace layout (fp32)
  float* ws = (float*)d_ws;
  const size_t NB = (size_t)NCn * HIDn;           // 6,400,000 floats per node buffer
  float* B0 = ws;
  float* B1 = ws + NB;
  float* B2 = ws + 2 * NB;
  float* B3 = ws + 3 * NB;
  float* B4 = ws + 4 * NB;
  float* sml = ws + 5 * NB;
  float*    sdot  = sml;                       // N*4
  float*    ddot  = sml + 200000;              // N*4
  unsigned* mbuf  = (unsigned*)(sml + 400000); // N*4
  float*    sden  = sml + 600000;              // N*4
  float*    ebuf  = sml + 800000;              // E*4 -> ends at 2,400,000
  float*    scoreB = sml + 2400000;            // [s0,s1,w0,w1]

  // CSR region: per graph {offs:50004, elist(int2):800000 ints, tmp:50000}
  const size_t CSR_BASE = 2400016, GSTRIDE = 900016;
  const size_t REQ_FLOATS = 5 * NB + CSR_BASE + 3 * GSTRIDE;   // 37,100,064
  const bool useCsr = ws_size >= REQ_FLOATS * sizeof(float);

  int*  offsG[3] = {nullptr, nullptr, nullptr};
  int2* elG[3]   = {nullptr, nullptr, nullptr};
  const int* eis[3] = {ei_cc, ei_dc, ei_cd};
  if (useCsr) {
    for (int g = 0; g < 3; ++g) {
      int* base = (int*)(sml + CSR_BASE + (size_t)g * GSTRIDE);
      offsG[g] = base;
      elG[g]   = (int2*)(base + 50004);
      int* tmp = base + 50004 + 800000;
      build_csr(stream, eis[g], offsG[g], elG[g], tmp);
    }
  }

  const dim3 gemmGrid((NCn + 63) / 64, HIDn / 64);

  // ---------------- layer 1 ----------------
  gemm_bias<256><<<gemmGrid, 256, 0, stream>>>(xc, W1c, b1c, B0, NCn, HIDn);
  gemm_bias<256><<<gemmGrid, 256, 0, stream>>>(xd, W1d, b1d, B1, NDn, HIDn);

  run_edge_att(stream, B0, B0, a1s_cc, a1d_cc, ei_cc, offsG[0], elG[0], NCn, NCn, B2, sdot, ddot, mbuf, sden, ebuf);
  run_edge_att(stream, B1, B0, a1s_dc, a1d_dc, ei_dc, offsG[1], elG[1], NDn, NCn, B3, sdot, ddot, mbuf, sden, ebuf);
  run_edge_att(stream, B0, B1, a1s_cd, a1d_cd, ei_cd, offsG[2], elG[2], NCn, NDn, B4, sdot, ddot, mbuf, sden, ebuf);

  hipMemsetAsync(scoreB, 0, 2 * sizeof(float), stream);
  score_lds<<<512, 256, 0, stream>>>(B2, k1W, k1b, q1, NCn, scoreB + 0);
  score_lds<<<512, 256, 0, stream>>>(B3, k1W, k1b, q1, NCn, scoreB + 1);
  softmax2_kernel<<<1, 1, 0, stream>>>(scoreB);
  combine2_elu<<<((int)NB + 255) / 256, 256, 0, stream>>>(B2, B3, scoreB, B0, (int)NB);
  elu_copy<<<((int)NB + 255) / 256, 256, 0, stream>>>(B4, B1, (int)NB);

  // ---------------- layer 2 ----------------
  gemm_bias<128><<<gemmGrid, 256, 0, stream>>>(B0, W2c, b2c, B2, NCn, HIDn);
  gemm_bias<128><<<gemmGrid, 256, 0, stream>>>(B1, W2d, b2d, B3, NDn, HIDn);

  run_edge_att(stream, B2, B2, a2s_cc, a2d_cc, ei_cc, offsG[0], elG[0], NCn, NCn, B4, sdot, ddot, mbuf, sden, ebuf);
  run_edge_att(stream, B3, B2, a2s_dc, a2d_dc, ei_dc, offsG[1], elG[1], NDn, NCn, B0, sdot, ddot, mbuf, sden, ebuf);
  run_edge_att(stream, B2, B3, a2s_cd, a2d_cd, ei_cd, offsG[2], elG[2], NCn, NDn, B1, sdot, ddot, mbuf, sden, ebuf);

  hipMemsetAsync(scoreB, 0, 2 * sizeof(float), stream);
  score_lds<<<512, 256, 0, stream>>>(B4, k2W, k2b, q2, NCn, scoreB + 0);
  score_lds<<<512, 256, 0, stream>>>(B0, k2W, k2b, q2, NCn, scoreB + 1);
  softmax2_kernel<<<1, 1, 0, stream>>>(scoreB);
  combine2_elu<<<((int)NB + 255) / 256, 256, 0, stream>>>(B4, B0, scoreB, B2, (int)NB);
  elu_copy<<<((int)NB + 255) / 256, 256, 0, stream>>>(B1, B3, (int)NB);

  // ---------------- projection + normalize ----------------
  proj_lds<true><<<512, 256, 0, stream>>>(B2, pW, pb, (float*)d_out, NCn);
  proj_lds<false><<<512, 256, 0, stream>>>(B3, pW, pb,
                                           (float*)d_out + (size_t)NCn * OUTn, NDn);
}

// Round 5
// 1505.772 us; speedup vs baseline: 2.5092x; 1.6119x over previous
//
#include <hip/hip_runtime.h>
#include <cmath>

#define DEVI static __device__ __forceinline__

constexpr int Dn = 32, HIDn = 128, OUTn = 64;
constexpr int NCn = 50000, NDn = 50000, En = 400000;

// monotonic float->uint mapping for atomicMax on floats (handles signs)
DEVI unsigned fmap(float f) {
  int i = __float_as_int(f);
  return (i < 0) ? ~((unsigned)i) : (((unsigned)i) | 0x80000000u);
}
DEVI float fdecode(unsigned u) {
  int i = (u & 0x80000000u) ? (int)(u & 0x7fffffffu) : (int)(~u);
  return __int_as_float(i);
}

// ---------------- GEMM: C[N,KO] = A[N,KI] @ W[KI,KO] + b (fp32 accum) ----
template<int KI>
__global__ __launch_bounds__(256)
void gemm_bias(const float* __restrict__ A, const float* __restrict__ W,
               const float* __restrict__ b, float* __restrict__ C,
               int N, int KO)
{
  __shared__ float At[32][68];   // A^T chunk: [k][row]
  __shared__ float Ws[32][68];   // W chunk:   [k][col]
  const int row0 = blockIdx.x * 64;
  const int col0 = blockIdx.y * 64;
  const int tid  = threadIdx.x;
  const int r0 = (tid >> 4) << 2;
  const int c0 = (tid & 15) << 2;
  float acc[4][4] = {{0.f, 0.f, 0.f, 0.f}};

  for (int k0 = 0; k0 < KI; k0 += 32) {
    {
      const int r  = tid >> 2;
      const int kq = (tid & 3) << 3;
      const int row = row0 + r;
      float tmp[8];
      if (row < N) {
        const float* ap = A + (size_t)row * KI + k0 + kq;
        #pragma unroll
        for (int i = 0; i < 8; ++i) tmp[i] = ap[i];
      } else {
        #pragma unroll
        for (int i = 0; i < 8; ++i) tmp[i] = 0.f;
      }
      #pragma unroll
      for (int i = 0; i < 8; ++i) At[kq + i][r] = tmp[i];
    }
    {
      const int k  = tid >> 3;
      const int cq = (tid & 7) << 3;
      const float* wp = W + (size_t)(k0 + k) * KO + col0 + cq;
      #pragma unroll
      for (int i = 0; i < 8; ++i) Ws[k][cq + i] = wp[i];
    }
    __syncthreads();
    #pragma unroll
    for (int k = 0; k < 32; ++k) {
      float av[4], wv[4];
      #pragma unroll
      for (int i = 0; i < 4; ++i) av[i] = At[k][r0 + i];
      #pragma unroll
      for (int j = 0; j < 4; ++j) wv[j] = Ws[k][c0 + j];
      #pragma unroll
      for (int i = 0; i < 4; ++i) {
        #pragma unroll
        for (int j = 0; j < 4; ++j) acc[i][j] += av[i] * wv[j];
      }
    }
    __syncthreads();
  }

  #pragma unroll
  for (int i = 0; i < 4; ++i) {
    const int row = row0 + r0 + i;
    if (row >= N) continue;
    #pragma unroll
    for (int j = 0; j < 4; ++j) {
      const int col = col0 + c0 + j;
      C[(size_t)row * KO + col] = acc[i][j] + b[col];
    }
  }
}

// ---- per-(node,head) dot: out[n,h] = sum_d h[n, h*32+d] * a[h*32+d] ----
__global__ void dot_ah(const float* __restrict__ h, const float* __restrict__ a,
                       float* __restrict__ out, int NH)
{
  int idx = blockIdx.x * blockDim.x + threadIdx.x;
  if (idx >= NH) return;
  int n = idx >> 2, hh = idx & 3;
  const float4* hp = (const float4*)(h + (size_t)n * HIDn + hh * Dn);
  const float4* ap = (const float4*)(a + hh * Dn);
  float s = 0.f;
  #pragma unroll
  for (int i = 0; i < 8; ++i) {
    float4 hv = hp[i], av = ap[i];
    s += hv.x * av.x + hv.y * av.y + hv.z * av.z + hv.w * av.w;
  }
  out[idx] = s;
}

// ================= CSR build (dst-bucketed edge lists) ===================
__global__ void hist_deg(const int* __restrict__ ei, int* __restrict__ deg)
{
  int e = blockIdx.x * blockDim.x + threadIdx.x;
  if (e < En) atomicAdd(&deg[ei[En + e]], 1);
}

// single-block exclusive scan: offs[0]=0, offs[i+1]=sum(deg[0..i])
__global__ void scan_offsets(const int* __restrict__ deg, int* __restrict__ offs, int n)
{
  __shared__ int wsum[16];
  __shared__ int carry_sh;
  int tid = threadIdx.x;
  if (tid == 0) { carry_sh = 0; offs[0] = 0; }
  __syncthreads();
  const int nw = blockDim.x >> 6;
  int lane = tid & 63, w = tid >> 6;
  for (int base = 0; base < n; base += blockDim.x) {
    int i = base + tid;
    int v = (i < n) ? deg[i] : 0;
    int x = v;
    #pragma unroll
    for (int off = 1; off < 64; off <<= 1) {
      int y = __shfl_up(x, off);
      if (lane >= off) x += y;
    }
    if (lane == 63) wsum[w] = x;
    __syncthreads();
    if (tid == 0) {
      int s = carry_sh;
      for (int ww = 0; ww < nw; ++ww) { int t = wsum[ww]; wsum[ww] = s; s += t; }
      carry_sh = s;
    }
    __syncthreads();
    if (i < n) offs[i + 1] = wsum[w] + x;
    __syncthreads();
  }
}

__global__ void fill_elist(const int* __restrict__ ei, const int* __restrict__ offs,
                           int* __restrict__ cursor, int2* __restrict__ elist)
{
  int e = blockIdx.x * blockDim.x + threadIdx.x;
  if (e >= En) return;
  int s = ei[e], d = ei[En + e];
  int p = atomicAdd(&cursor[d], 1);
  elist[offs[d] + p] = make_int2(s, e);
}

// ==== FUSED edge attention (CSR): online segmax+denom, then gather =======
// One wave per dst. Phase A: head=lane&3, 16 edge-slots in parallel,
// flash-style online max/denominator. Phase B: head=lane>>4 (2 channels
// per lane), alpha recomputed from sdot/ddot (wave-uniform broadcasts).
__global__ __launch_bounds__(256)
void csr_att(const int* __restrict__ offs, const int2* __restrict__ elist,
             const float* __restrict__ sdot, const float* __restrict__ ddot,
             const float* __restrict__ hsrc, float* __restrict__ out, int Ndst)
{
  int wave = (blockIdx.x * 256 + threadIdx.x) >> 6;
  if (wave >= Ndst) return;
  const int lane = threadIdx.x & 63;
  const int dst = wave;
  const int i0 = offs[dst], i1 = offs[dst + 1];

  // ---- phase A: per-head running max m and denominator den ----
  const int hA = lane & 3;
  const float ddA = ddot[dst * 4 + hA];
  float m = -INFINITY, den = 0.f;
  for (int base = i0; base < i1; base += 16) {
    int i = base + (lane >> 2);
    float l;
    if (i < i1) {
      int srcn = elist[i].x;
      float lv = sdot[srcn * 4 + hA] + ddA;
      l = (lv > 0.f) ? lv : 0.2f * lv;            // leaky_relu(0.2)
    } else l = -INFINITY;
    float mx = l;
    #pragma unroll
    for (int off = 4; off < 64; off <<= 1) mx = fmaxf(mx, __shfl_xor(mx, off));
    float mnew = fmaxf(m, mx);                    // finite: >=1 valid edge/chunk
    float ex = __expf(l - mnew);                  // padded lanes: exp(-inf)=0
    #pragma unroll
    for (int off = 4; off < 64; off <<= 1) ex += __shfl_xor(ex, off);
    den = den * __expf(m - mnew) + ex;            // first iter: exp(-inf)=0
    m = mnew;
  }

  // ---- redistribute: lane h (h<4) holds head-h stats ----
  const int hB = lane >> 4;
  float mB   = __shfl(m, hB);
  float dinv = __shfl(den, hB);
  dinv = 1.f / (dinv + 1e-16f);
  const float ddB = ddot[dst * 4 + hB];

  // ---- phase B: gather alpha * h_src, fused relu ----
  float a0 = 0.f, a1 = 0.f;
  for (int i = i0; i < i1; ++i) {
    int2 se = elist[i];
    float lv = sdot[se.x * 4 + hB] + ddB;
    lv = (lv > 0.f) ? lv : 0.2f * lv;
    float alpha = __expf(lv - mB) * dinv;
    float2 hv = *(const float2*)(hsrc + (size_t)se.x * HIDn + lane * 2);
    a0 += hv.x * alpha;
    a1 += hv.y * alpha;
  }
  float2 o2;
  o2.x = fmaxf(a0, 0.f);
  o2.y = fmaxf(a1, 0.f);
  *(float2*)(out + (size_t)dst * HIDn + lane * 2) = o2;
}

// ---- fallback path (atomic scatter), used only if ws too small ----------
__global__ void edge_logit_max(const int* __restrict__ ei,
                               const float* __restrict__ sdot,
                               const float* __restrict__ ddot,
                               unsigned* __restrict__ m)
{
  int e = blockIdx.x * blockDim.x + threadIdx.x;
  if (e >= En) return;
  int s = ei[e], d = ei[En + e];
  #pragma unroll
  for (int hh = 0; hh < 4; ++hh) {
    float l = sdot[s * 4 + hh] + ddot[d * 4 + hh];
    l = (l > 0.f) ? l : 0.2f * l;
    atomicMax(&m[d * 4 + hh], fmap(l));
  }
}

__global__ void edge_exp_sum(const int* __restrict__ ei,
                             const float* __restrict__ sdot,
                             const float* __restrict__ ddot,
                             const unsigned* __restrict__ m,
                             float* __restrict__ sden,
                             float* __restrict__ ebuf)
{
  int e = blockIdx.x * blockDim.x + threadIdx.x;
  if (e >= En) return;
  int s = ei[e], d = ei[En + e];
  #pragma unroll
  for (int hh = 0; hh < 4; ++hh) {
    float l = sdot[s * 4 + hh] + ddot[d * 4 + hh];
    l = (l > 0.f) ? l : 0.2f * l;
    float ex = expf(fminf(l - fdecode(m[d * 4 + hh]), 0.f));
    ebuf[e * 4 + hh] = ex;
    atomicAdd(&sden[d * 4 + hh], ex);
  }
}

__global__ __launch_bounds__(256)
void edge_scatter(const int* __restrict__ ei, const float* __restrict__ hsrc,
                  const float* __restrict__ ebuf, const float* __restrict__ sden,
                  float* __restrict__ out)
{
  int gid  = blockIdx.x * 256 + threadIdx.x;
  int e    = gid >> 6;
  if (e >= En) return;
  int lane = gid & 63;
  int s = ei[e], d = ei[En + e];
  #pragma unroll
  for (int half = 0; half < 2; ++half) {
    int c  = lane + half * 64;
    int hh = c >> 5;
    float alpha = ebuf[e * 4 + hh] / (sden[d * 4 + hh] + 1e-16f);
    atomicAdd(&out[(size_t)d * HIDn + c], hsrc[(size_t)s * HIDn + c] * alpha);
  }
}

__global__ void relu_k(float* __restrict__ x, int n)
{
  int i = blockIdx.x * blockDim.x + threadIdx.x;
  if (i < n) x[i] = fmaxf(x[i], 0.f);
}

// ---- semantic-attention score, kW in LDS; 4 accumulators for ILP --------
// score = (1/N) * sum_n sum_c q[c]*tanh((o@kW+kb)[n,c])  -- separable in c.
// Even blocks: c in [0,64); odd blocks: [64,128).
__global__ __launch_bounds__(256)
void score_lds(const float* __restrict__ o, const float* __restrict__ kW,
               const float* __restrict__ kb, const float* __restrict__ q,
               int N, float* __restrict__ slot)
{
  __shared__ float kWs[128 * 64];
  __shared__ float rows[4][128];
  __shared__ float kbs[64], qs[64];
  __shared__ float partw[4];
  const int tid = threadIdx.x;
  const int ch  = blockIdx.x & 1;
  for (int i = tid * 4; i < 8192; i += 1024) {
    int k = i >> 6, cl = i & 63;
    *(float4*)&kWs[i] = *(const float4*)&kW[k * 128 + ch * 64 + cl];
  }
  if (tid < 64) { kbs[tid] = kb[ch * 64 + tid]; qs[tid] = q[ch * 64 + tid]; }
  __syncthreads();
  const int nl = tid >> 6, cl = tid & 63;
  const int nb = blockIdx.x >> 1, NBLK = gridDim.x >> 1;
  float part = 0.f;
  for (int n0 = nb * 4; n0 < N; n0 += NBLK * 4) {
    int node = n0 + nl;
    rows[nl][cl]      = (node < N) ? o[(size_t)node * HIDn + cl]      : 0.f;
    rows[nl][cl + 64] = (node < N) ? o[(size_t)node * HIDn + cl + 64] : 0.f;
    __syncthreads();
    float a0 = kbs[cl], a1 = 0.f, a2 = 0.f, a3 = 0.f;
    #pragma unroll
    for (int k = 0; k < 128; k += 4) {
      float4 rv = *(const float4*)&rows[nl][k];
      a0 += rv.x * kWs[(k + 0) * 64 + cl];
      a1 += rv.y * kWs[(k + 1) * 64 + cl];
      a2 += rv.z * kWs[(k + 2) * 64 + cl];
      a3 += rv.w * kWs[(k + 3) * 64 + cl];
    }
    float acc = (a0 + a1) + (a2 + a3);
    if (node < N) part += qs[cl] * tanhf(acc);
    __syncthreads();
  }
  #pragma unroll
  for (int off = 32; off > 0; off >>= 1) part += __shfl_down(part, off);
  if (cl == 0) partw[nl] = part;
  __syncthreads();
  if (tid == 0)
    atomicAdd(slot, (partw[0] + partw[1] + partw[2] + partw[3]) * (1.f / (float)N));
}

__global__ void softmax2_kernel(float* sb)   // sb[0],sb[1] -> weights sb[2],sb[3]
{
  float s0 = sb[0], s1 = sb[1];
  float mx = fmaxf(s0, s1);
  float e0 = expf(s0 - mx), e1 = expf(s1 - mx);
  float inv = 1.f / (e0 + e1);
  sb[2] = e0 * inv;
  sb[3] = e1 * inv;
}

__global__ void combine2_elu(const float* __restrict__ a, const float* __restrict__ b,
                             const float* __restrict__ w, float* __restrict__ out, int n)
{
  int i = blockIdx.x * blockDim.x + threadIdx.x;
  if (i >= n) return;
  float x = w[2] * a[i] + w[3] * b[i];
  out[i] = (x > 0.f) ? x : expm1f(x);
}

__global__ void elu_copy(const float* __restrict__ a, float* __restrict__ out, int n)
{
  int i = blockIdx.x * blockDim.x + threadIdx.x;
  if (i >= n) return;
  float x = a[i];
  out[i] = (x > 0.f) ? x : expm1f(x);
}

// ---- final projection (+ optional L2 normalize), pW staged in LDS -------
template<bool NORM>
__global__ __launch_bounds__(256)
void proj_lds(const float* __restrict__ feat, const float* __restrict__ pW,
              const float* __restrict__ pb, float* __restrict__ out, int N)
{
  __shared__ float pWs[128 * 64];
  __shared__ float rows[4][128];
  __shared__ float pbs[64];
  const int tid = threadIdx.x;
  for (int i = tid * 4; i < 8192; i += 1024)
    *(float4*)&pWs[i] = *(const float4*)&pW[i];
  if (tid < 64) pbs[tid] = pb[tid];
  __syncthreads();
  const int wid = tid >> 6, lane = tid & 63;
  for (int n0 = blockIdx.x * 4; n0 < N; n0 += gridDim.x * 4) {
    int node = n0 + wid;
    if (node < N) {
      rows[wid][lane]      = feat[(size_t)node * HIDn + lane];
      rows[wid][lane + 64] = feat[(size_t)node * HIDn + lane + 64];
    }
    __syncthreads();
    if (node < N) {
      float a0 = pbs[lane], a1 = 0.f, a2 = 0.f, a3 = 0.f;
      #pragma unroll
      for (int k = 0; k < 128; k += 4) {
        float4 rv = *(const float4*)&rows[wid][k];
        a0 += rv.x * pWs[(k + 0) * 64 + lane];
        a1 += rv.y * pWs[(k + 1) * 64 + lane];
        a2 += rv.z * pWs[(k + 2) * 64 + lane];
        a3 += rv.w * pWs[(k + 3) * 64 + lane];
      }
      float acc = (a0 + a1) + (a2 + a3);
      if (NORM) {
        float ss = acc * acc;
        #pragma unroll
        for (int off = 1; off < 64; off <<= 1) ss += __shfl_xor(ss, off);
        acc *= 1.f / fmaxf(sqrtf(ss), 1e-12f);
      }
      out[(size_t)node * OUTn + lane] = acc;
    }
    __syncthreads();
  }
}

// ---- one full GAT edge-attention op -------------------------------------
static void run_edge_att(hipStream_t stream,
                         const float* hsrc, const float* hdst,
                         const float* a_s, const float* a_d, const int* ei,
                         const int* offs, const int2* elist,   // null -> fallback
                         int Nsrc, int Ndst, float* outb,
                         float* sdot, float* ddot, unsigned* mbuf,
                         float* sden, float* ebuf)
{
  dot_ah<<<(Nsrc * 4 + 255) / 256, 256, 0, stream>>>(hsrc, a_s, sdot, Nsrc * 4);
  dot_ah<<<(Ndst * 4 + 255) / 256, 256, 0, stream>>>(hdst, a_d, ddot, Ndst * 4);
  if (elist) {
    csr_att<<<(Ndst + 3) / 4, 256, 0, stream>>>(offs, elist, sdot, ddot, hsrc, outb, Ndst);
  } else {
    hipMemsetAsync(mbuf, 0, (size_t)Ndst * 4 * sizeof(unsigned), stream);
    edge_logit_max<<<(En + 255) / 256, 256, 0, stream>>>(ei, sdot, ddot, mbuf);
    hipMemsetAsync(sden, 0, (size_t)Ndst * 4 * sizeof(float), stream);
    edge_exp_sum<<<(En + 255) / 256, 256, 0, stream>>>(ei, sdot, ddot, mbuf, sden, ebuf);
    hipMemsetAsync(outb, 0, (size_t)Ndst * HIDn * sizeof(float), stream);
    edge_scatter<<<((size_t)En * 64 + 255) / 256, 256, 0, stream>>>(ei, hsrc, ebuf, sden, outb);
    relu_k<<<((size_t)Ndst * HIDn + 255) / 256, 256, 0, stream>>>(outb, Ndst * HIDn);
  }
}

static void build_csr(hipStream_t stream, const int* ei, int* offs, int2* elist, int* tmp)
{
  hipMemsetAsync(tmp, 0, 50000 * sizeof(int), stream);
  hist_deg<<<(En + 255) / 256, 256, 0, stream>>>(ei, tmp);
  scan_offsets<<<1, 1024, 0, stream>>>(tmp, offs, 50000);
  hipMemsetAsync(tmp, 0, 50000 * sizeof(int), stream);
  fill_elist<<<(En + 255) / 256, 256, 0, stream>>>(ei, offs, tmp, elist);
}

extern "C" void kernel_launch(void* const* d_in, const int* in_sizes, int n_in,
                              void* d_out, int out_size, void* d_ws, size_t ws_size,
                              hipStream_t stream)
{
  const float* xc    = (const float*)d_in[0];
  const float* xd    = (const float*)d_in[1];
  const int*   ei_cc = (const int*)d_in[2];
  const int*   ei_dc = (const int*)d_in[3];
  const int*   ei_cd = (const int*)d_in[4];
  const float* W1c = (const float*)d_in[5];  const float* b1c = (const float*)d_in[6];
  const float* W1d = (const float*)d_in[7];  const float* b1d = (const float*)d_in[8];
  const float* a1s_cc = (const float*)d_in[9];  const float* a1d_cc = (const float*)d_in[10];
  const float* a1s_dc = (const float*)d_in[11]; const float* a1d_dc = (const float*)d_in[12];
  const float* a1s_cd = (const float*)d_in[13]; const float* a1d_cd = (const float*)d_in[14];
  const float* k1W = (const float*)d_in[15]; const float* k1b = (const float*)d_in[16];
  const float* q1  = (const float*)d_in[17];
  const float* W2c = (const float*)d_in[18]; const float* b2c = (const float*)d_in[19];
  const float* W2d = (const float*)d_in[20]; const float* b2d = (const float*)d_in[21];
  const float* a2s_cc = (const float*)d_in[22]; const float* a2d_cc = (const float*)d_in[23];
  const float* a2s_dc = (const float*)d_in[24]; const float* a2d_dc = (const float*)d_in[25];
  const float* a2s_cd = (const float*)d_in[26]; const float* a2d_cd = (const float*)d_in[27];
  const float* k2W = (const float*)d_in[28]; const float* k2b = (const float*)d_in[29];
  const float* q2  = (const float*)d_in[30];
  const float* pW  = (const float*)d_in[31]; const float* pb  = (const float*)d_in[32];

  // workspace layout (fp32)
  float* ws = (float*)d_ws;
  const size_t NB = (size_t)NCn * HIDn;           // 6,400,000 floats per node buffer
  float* B0 = ws;
  float* B1 = ws + NB;
  float* B2 = ws + 2 * NB;
  float* B3 = ws + 3 * NB;
  float* B4 = ws + 4 * NB;
  float* sml = ws + 5 * NB;
  float*    sdot  = sml;                       // N*4
  float*    ddot  = sml + 200000;              // N*4
  unsigned* mbuf  = (unsigned*)(sml + 400000); // N*4 (fallback only)
  float*    sden  = sml + 600000;              // N*4 (fallback only)
  float*    ebuf  = sml + 800000;              // E*4 (fallback only)
  float*    scoreB = sml + 2400000;            // [s0,s1,w0,w1]

  // CSR region: per graph {offs:50004, elist(int2):800000 ints, tmp:50000}
  const size_t CSR_BASE = 2400016, GSTRIDE = 900016;
  const size_t REQ_FLOATS = 5 * NB + CSR_BASE + 3 * GSTRIDE;   // 37,100,064
  const bool useCsr = ws_size >= REQ_FLOATS * sizeof(float);

  int*  offsG[3] = {nullptr, nullptr, nullptr};
  int2* elG[3]   = {nullptr, nullptr, nullptr};
  const int* eis[3] = {ei_cc, ei_dc, ei_cd};
  if (useCsr) {
    for (int g = 0; g < 3; ++g) {
      int* base = (int*)(sml + CSR_BASE + (size_t)g * GSTRIDE);
      offsG[g] = base;
      elG[g]   = (int2*)(base + 50004);
      int* tmp = base + 50004 + 800000;
      build_csr(stream, eis[g], offsG[g], elG[g], tmp);
    }
  }

  const dim3 gemmGrid((NCn + 63) / 64, HIDn / 64);

  // ---------------- layer 1 ----------------
  gemm_bias<256><<<gemmGrid, 256, 0, stream>>>(xc, W1c, b1c, B0, NCn, HIDn);
  gemm_bias<256><<<gemmGrid, 256, 0, stream>>>(xd, W1d, b1d, B1, NDn, HIDn);

  run_edge_att(stream, B0, B0, a1s_cc, a1d_cc, ei_cc, offsG[0], elG[0], NCn, NCn, B2, sdot, ddot, mbuf, sden, ebuf);
  run_edge_att(stream, B1, B0, a1s_dc, a1d_dc, ei_dc, offsG[1], elG[1], NDn, NCn, B3, sdot, ddot, mbuf, sden, ebuf);
  run_edge_att(stream, B0, B1, a1s_cd, a1d_cd, ei_cd, offsG[2], elG[2], NCn, NDn, B4, sdot, ddot, mbuf, sden, ebuf);

  hipMemsetAsync(scoreB, 0, 2 * sizeof(float), stream);
  score_lds<<<1024, 256, 0, stream>>>(B2, k1W, k1b, q1, NCn, scoreB + 0);
  score_lds<<<1024, 256, 0, stream>>>(B3, k1W, k1b, q1, NCn, scoreB + 1);
  softmax2_kernel<<<1, 1, 0, stream>>>(scoreB);
  combine2_elu<<<((int)NB + 255) / 256, 256, 0, stream>>>(B2, B3, scoreB, B0, (int)NB);
  elu_copy<<<((int)NB + 255) / 256, 256, 0, stream>>>(B4, B1, (int)NB);

  // ---------------- layer 2 ----------------
  gemm_bias<128><<<gemmGrid, 256, 0, stream>>>(B0, W2c, b2c, B2, NCn, HIDn);
  gemm_bias<128><<<gemmGrid, 256, 0, stream>>>(B1, W2d, b2d, B3, NDn, HIDn);

  run_edge_att(stream, B2, B2, a2s_cc, a2d_cc, ei_cc, offsG[0], elG[0], NCn, NCn, B4, sdot, ddot, mbuf, sden, ebuf);
  run_edge_att(stream, B3, B2, a2s_dc, a2d_dc, ei_dc, offsG[1], elG[1], NDn, NCn, B0, sdot, ddot, mbuf, sden, ebuf);
  run_edge_att(stream, B2, B3, a2s_cd, a2d_cd, ei_cd, offsG[2], elG[2], NCn, NDn, B1, sdot, ddot, mbuf, sden, ebuf);

  hipMemsetAsync(scoreB, 0, 2 * sizeof(float), stream);
  score_lds<<<1024, 256, 0, stream>>>(B4, k2W, k2b, q2, NCn, scoreB + 0);
  score_lds<<<1024, 256, 0, stream>>>(B0, k2W, k2b, q2, NCn, scoreB + 1);
  softmax2_kernel<<<1, 1, 0, stream>>>(scoreB);
  combine2_elu<<<((int)NB + 255) / 256, 256, 0, stream>>>(B4, B0, scoreB, B2, (int)NB);
  elu_copy<<<((int)NB + 255) / 256, 256, 0, stream>>>(B1, B3, (int)NB);

  // ---------------- projection + normalize ----------------
  proj_lds<true><<<512, 256, 0, stream>>>(B2, pW, pb, (float*)d_out, NCn);
  proj_lds<false><<<512, 256, 0, stream>>>(B3, pW, pb,
                                           (float*)d_out + (size_t)NCn * OUTn, NDn);
}